// Round 9
// baseline (361.222 us; speedup 1.0000x reference)
//
#include <hip/hip_runtime.h>
#include <hip/hip_bf16.h>
#include <stdint.h>

#define DI __device__ __forceinline__

typedef __bf16 bf16x8 __attribute__((ext_vector_type(8)));
typedef __bf16 bf16x4 __attribute__((ext_vector_type(4)));
typedef float f32x16 __attribute__((ext_vector_type(16)));
typedef float f32x2 __attribute__((ext_vector_type(2)));

DI float bf2f(unsigned short u){ return __uint_as_float(((unsigned int)u)<<16); }
DI unsigned short f2bf(float f){
  unsigned int x = __float_as_uint(f);
  x += 0x7fffu + ((x>>16)&1u);           // RNE; inputs are finite
  return (unsigned short)(x>>16);
}
DI float sigmoidf_(float x){ return 1.0f/(1.0f + __expf(-x)); }
DI float tanhf_(float x){ return 2.0f/(1.0f + __expf(-2.0f*x)) - 1.0f; }  // NaN-safe at both extremes

DI void gld_lds16(const void* g, void* l){
  __builtin_amdgcn_global_load_lds((const __attribute__((address_space(1))) void*)g,
                                   (__attribute__((address_space(3))) void*)l, 16, 0, 0);
}
DI f32x16 mfma32(bf16x8 a, bf16x8 b, f32x16 c){
  return __builtin_amdgcn_mfma_f32_32x32x16_bf16(a, b, c, 0, 0, 0);
}

// ============ weight prep: pack to MFMA B-fragment order, bf16 ============
// frag layout: [tile-linear][lane 64][j 8]; per frag: col n=(l&31)+32*nt, k=(l>>5)*8+j
// conv1: 4 frags (K=64, N=32), /255 folded in. kg = ky*8+kx = kk*16+(l>>5)*8+j
__global__ __launch_bounds__(256) void k_prep_w1(const float* __restrict__ w1, unsigned short* __restrict__ o){
  int idx = blockIdx.x*256 + threadIdx.x;          // 2048 = 4 kk * 512
  int j=idx&7, l=(idx>>3)&63, kk=idx>>9;
  int oc=l&31, kg=kk*16+((l>>5)<<3)+j;
  o[idx] = f2bf(w1[oc*64 + kg] * (1.0f/255.0f));
}
__global__ __launch_bounds__(256) void k_prep_w2(const float* __restrict__ w2, unsigned short* __restrict__ o){
  int idx = blockIdx.x*256 + threadIdx.x;          // 32768 = 16 shifts * 2 kh * 2 nt * 512
  int j=idx&7, l=(idx>>3)&63, nt=(idx>>9)&1, kh=(idx>>10)&1, s=idx>>11;
  int oc=nt*32+(l&31), ic=kh*16+(l>>5)*8+j, ky=s>>2, kx=s&3;
  o[idx] = f2bf(w2[((oc*32+ic)*4+ky)*4+kx]);
}
__global__ __launch_bounds__(256) void k_prep_w3(const float* __restrict__ w3, unsigned short* __restrict__ o){
  int idx = blockIdx.x*256 + threadIdx.x;          // 36864 = 9 shifts * 4 kh * 2 nt * 512
  int j=idx&7, l=(idx>>3)&63, nt=(idx>>9)&1, kh=(idx>>10)&3, s=idx>>12;
  int oc=nt*32+(l&31), ic=kh*16+(l>>5)*8+j, ky=s/3, kx=s-ky*3;
  o[idx] = f2bf(w3[((oc*64+ic)*3+ky)*3+kx]);
}
// FC: A3 k' = pos*64 + c ; fc_w k = c*49 + pos ; hi at [0,SZ), lo residual at [SZ,2SZ)
__global__ __launch_bounds__(512) void k_prep_fc(const float* __restrict__ fcw, unsigned short* __restrict__ o){
  int tid=threadIdx.x, ks=blockIdx.x, nt=blockIdx.y;   // grid (196,16)
  int j=tid&7, l=tid>>3;
  int n=nt*32+(l&31), k=ks*16+(l>>5)*8+j;
  int c=k&63, pos=k>>6;
  float wv = fcw[(size_t)n*3136 + c*49 + pos];
  unsigned short hi = f2bf(wv);
  int idx = (nt*196+ks)*512 + tid;
  o[idx] = hi;
  o[1605632 + idx] = f2bf(wv - bf2f(hi));
}
__global__ __launch_bounds__(512) void k_prep_gx(const float* __restrict__ wih, unsigned short* __restrict__ o){
  int tid=threadIdx.x, ks=blockIdx.x, nt=blockIdx.y;   // grid (32,12)
  int j=tid&7, l=tid>>3;
  int n=nt*32+(l&31), k=ks*16+(l>>5)*8+j;
  float wv = wih[(size_t)n*512 + k];
  unsigned short hi = f2bf(wv);
  int idx = (nt*32+ks)*512 + tid;
  o[idx] = hi;
  o[196608 + idx] = f2bf(wv - bf2f(hi));
}

// ============ conv1 (MFMA): x[.,1,84,84] -> 8x8 s4 + relu -> A1[nloc][400 pos][32 ic] bf16
// 4 waves/block, one image per wave; image bf16 in LDS [84][88]; /255 folded into weights.
__global__ __launch_bounds__(256) void k_conv1(const float* __restrict__ x,
    const unsigned short* __restrict__ w1p, const float* __restrict__ b,
    unsigned short* __restrict__ a1, int nbase)
{
  __shared__ __align__(16) char imgs[4*14784];     // 4 x [84 rows][88 cols] bf16
  const int tid=threadIdx.x, l=tid&63, w=tid>>6;
  const int nloc = blockIdx.x*4 + w;
  char* myimg = imgs + w*14784;
  const float* xp = x + (size_t)(nbase+nloc)*7056;

  for (int it=0; it<28; ++it){
    int idx4 = l + it*64;                          // over 1764 float4s
    if (idx4 < 1764){
      float4 v = *(const float4*)(xp + idx4*4);
      int row = idx4/21, rem = idx4 - row*21;      // 21 float4s per 84-col row
      ushort4 u; u.x=f2bf(v.x); u.y=f2bf(v.y); u.z=f2bf(v.z); u.w=f2bf(v.w);
      *(ushort4*)(myimg + row*176 + rem*8) = u;
    }
  }

  bf16x8 wb[4];
  #pragma unroll
  for (int kk=0;kk<4;kk++) wb[kk] = *(const bf16x8*)(w1p + (kk*64 + l)*8);
  const float bias = b[l&31];
  asm volatile("s_waitcnt lgkmcnt(0)" ::: "memory");   // staging ds_writes drained

  const int kyh = (l>>5);
  unsigned short* obase = a1 + (size_t)nloc*12800;
  for (int mt=0; mt<13; ++mt){
    int p = mt*32 + (l&31);
    p = min(p, 399);                               // clamped lanes broadcast-read row 399
    const int oy = p/20, ox = p - oy*20;
    const int rbyte = oy*4*176 + ox*8;
    f32x16 acc = {};
    #pragma unroll
    for (int kk=0;kk<4;kk++){
      const int a = rbyte + (kk*2 + kyh)*176;
      bf16x8 af;
      *(bf16x4*)&af       = *(const bf16x4*)(myimg + a);
      *((bf16x4*)&af + 1) = *(const bf16x4*)(myimg + a + 8);
      acc = mfma32(af, wb[kk], acc);
    }
    const int oc = l&31;
    #pragma unroll
    for (int rg=0;rg<16;rg++){
      int row = (rg&3) + 8*(rg>>2) + 4*kyh;
      int pos = mt*32 + row;
      if (pos < 400)
        obase[pos*32 + oc] = f2bf(fmaxf(acc[rg] + bias, 0.f));
    }
  }
}

// ============ conv2: A1[nloc][400][32] -> 4x4 s2 + relu -> A2[nbase+nloc][81][64] (MFMA)
__global__ __launch_bounds__(256) void k_conv2(const unsigned short* __restrict__ a1,
    const unsigned short* __restrict__ w2p, const float* __restrict__ b2,
    unsigned short* __restrict__ a2, int nbase)
{
  extern __shared__ __align__(16) char smem[];   // 4*25600
  const int tid=threadIdx.x, l=tid&63, w=tid>>6;
  const int nloc = blockIdx.x*4 + w;
  char* myimg = smem + w*25600;
  const char* gimg = (const char*)(a1 + (size_t)nloc*12800);
  #pragma unroll
  for (int i=0;i<25;i++){
    int o = i*1024 + l*16;
    int q = o ^ (((o>>7)&7)<<4);     // involutive swizzle, pre-applied to source
    gld_lds16(gimg + q, myimg + i*1024);
  }
  __syncthreads();
  int rbase[3];
  #pragma unroll
  for (int mt=0;mt<3;mt++){
    int r = mt*32 + (l&31);
    int oy=r/9, ox=r-oy*9;
    rbase[mt] = 40*oy + 2*ox;        // in_pos at ky=kx=0
  }
  const int grp16 = (l>>5)*16;
  f32x16 acc[3][2] = {};
  #pragma unroll
  for (int ky=0;ky<4;ky++){
    #pragma unroll
    for (int kx=0;kx<4;kx++){
      const int s = ky*4+kx;
      #pragma unroll
      for (int kh=0;kh<2;kh++){
        bf16x8 b0 = *(const bf16x8*)(w2p + (((s*2+kh)*2+0)*64 + l)*8);
        bf16x8 b1 = *(const bf16x8*)(w2p + (((s*2+kh)*2+1)*64 + l)*8);
        #pragma unroll
        for (int mt=0;mt<3;mt++){
          int ip = rbase[mt] + ky*20 + kx;
          ip = min(ip, 399);                       // pad rows read junk; outputs discarded
          int byte = (ip*64 + kh*32 + grp16) ^ (((ip>>1)&7)<<4);
          bf16x8 af = *(const bf16x8*)(myimg + byte);
          acc[mt][0] = mfma32(af, b0, acc[mt][0]);
          acc[mt][1] = mfma32(af, b1, acc[mt][1]);
        }
      }
    }
  }
  const float bias0 = b2[l&31], bias1 = b2[32+(l&31)];
  unsigned short* ob = (unsigned short*)myimg;     // reuse as [96][64] out stage
  #pragma unroll
  for (int mt=0;mt<3;mt++){
    #pragma unroll
    for (int rg=0;rg<16;rg++){
      int r = mt*32 + (rg&3) + 8*(rg>>2) + 4*(l>>5);
      ob[r*64 + (l&31)]      = f2bf(fmaxf(acc[mt][0][rg]+bias0,0.f));
      ob[r*64 + 32 + (l&31)] = f2bf(fmaxf(acc[mt][1][rg]+bias1,0.f));
    }
  }
  asm volatile("s_waitcnt lgkmcnt(0)" ::: "memory");
  const uint4* s4 = (const uint4*)ob;
  uint4* d4 = (uint4*)(a2 + (size_t)(nbase+nloc)*5184);
  #pragma unroll
  for (int i=0;i<11;i++){
    int c = i*64 + l;
    if (c < 648) d4[c] = s4[c];
  }
}

// ============ conv3: A2[n][81][64] -> 3x3 s1 + relu -> A3[n][49][64] bf16 (MFMA)
__global__ __launch_bounds__(256) void k_conv3(const unsigned short* __restrict__ a2,
    const unsigned short* __restrict__ w3p, const float* __restrict__ b3,
    unsigned short* __restrict__ a3)
{
  __shared__ __align__(16) char smem3[4*11264];
  const int tid=threadIdx.x, l=tid&63, w=tid>>6;
  const int n = blockIdx.x*4 + w;
  char* myimg = smem3 + w*11264;
  const char* gimg = (const char*)(a2 + (size_t)n*5184);
  #pragma unroll
  for (int i=0;i<11;i++){
    int c = i*64 + l;
    int cc = min(c, 647);
    int o = cc*16;
    int q = o ^ (((o>>7)&7)<<4);
    gld_lds16(gimg + q, myimg + i*1024);
  }
  __syncthreads();
  int base[2];
  #pragma unroll
  for (int mt=0;mt<2;mt++){
    int r = mt*32 + (l&31);
    int oy=r/7, ox=r-oy*7;
    base[mt] = oy*9 + ox;
  }
  const int grp16 = (l>>5)*16;
  f32x16 acc[2][2] = {};
  #pragma unroll
  for (int ky=0;ky<3;ky++){
    #pragma unroll
    for (int kx=0;kx<3;kx++){
      const int s = ky*3+kx;
      #pragma unroll
      for (int kh=0;kh<4;kh++){
        bf16x8 b0 = *(const bf16x8*)(w3p + (((s*4+kh)*2+0)*64 + l)*8);
        bf16x8 b1 = *(const bf16x8*)(w3p + (((s*4+kh)*2+1)*64 + l)*8);
        #pragma unroll
        for (int mt=0;mt<2;mt++){
          int ip = min(base[mt] + ky*9 + kx, 80);
          int byte = (ip*128 + kh*32 + grp16) ^ ((ip&7)<<4);
          bf16x8 af = *(const bf16x8*)(myimg + byte);
          acc[mt][0] = mfma32(af, b0, acc[mt][0]);
          acc[mt][1] = mfma32(af, b1, acc[mt][1]);
        }
      }
    }
  }
  const float bias0 = b3[l&31], bias1 = b3[32+(l&31)];
  unsigned short* ob = (unsigned short*)myimg;     // [49][64]
  #pragma unroll
  for (int mt=0;mt<2;mt++){
    #pragma unroll
    for (int rg=0;rg<16;rg++){
      int r = mt*32 + (rg&3) + 8*(rg>>2) + 4*(l>>5);
      if (r < 49){
        ob[r*64 + (l&31)]      = f2bf(fmaxf(acc[mt][0][rg]+bias0,0.f));
        ob[r*64 + 32 + (l&31)] = f2bf(fmaxf(acc[mt][1][rg]+bias1,0.f));
      }
    }
  }
  asm volatile("s_waitcnt lgkmcnt(0)" ::: "memory");
  const uint4* s4 = (const uint4*)ob;
  uint4* d4 = (uint4*)(a3 + (size_t)n*3136);
  #pragma unroll
  for (int i=0;i<7;i++){
    int c = i*64 + l;
    if (c < 392) d4[c] = s4[c];
  }
}

// ============ GEMM: out[M,N] = act(A[M,K](bf16) @ (Whi+Wlo)^frag + bias) ; BM=128 BN=64 BK=32
template<bool RELU, bool OBF16>
__global__ __launch_bounds__(256) void k_gemm(const unsigned short* __restrict__ A, int K,
    const unsigned short* __restrict__ Wp, int loOff, const float* __restrict__ bias,
    void* __restrict__ out, int N)
{
  __shared__ __align__(16) char ab[2][8192];      // [128 rows][32 bf16] x2
  const int tid=threadIdx.x, l=tid&63, w=tid>>6;
  const int m0=blockIdx.y*128, n0=blockIdx.x*64;
  const int KS=K>>4, T=K>>5;
  const int mh=w&1, ntl=w>>1;
  const int ntg = blockIdx.x*2 + ntl;
  const char* Ab = (const char*)A;

  f32x16 acc[2] = {};
  bf16x8 bh0, bh1, bl0, bl1, nh0, nh1, nl0, nl1;

  #pragma unroll
  for (int i=0;i<2;i++){
    int o = (w*2+i)*1024 + l*16;
    int q = o ^ (((o>>7)&7)<<4);
    int row = q>>6, kc=(q>>4)&3;
    gld_lds16(Ab + ((size_t)(m0+row)*K)*2 + kc*16, ab[0] + (w*2+i)*1024);
  }
  {
    const unsigned short* p0 = Wp + ((size_t)(ntg*KS)*64 + l)*8;
    bh0 = *(const bf16x8*)(p0);
    bh1 = *(const bf16x8*)(p0 + 512);
    bl0 = *(const bf16x8*)(p0 + loOff);
    bl1 = *(const bf16x8*)(p0 + loOff + 512);
  }
  __syncthreads();

  for (int t=0;t<T;t++){
    const int cb = t&1;
    if (t+1 < T){
      #pragma unroll
      for (int i=0;i<2;i++){
        int o = (w*2+i)*1024 + l*16;
        int q = o ^ (((o>>7)&7)<<4);
        int row = q>>6, kc=(q>>4)&3;
        gld_lds16(Ab + ((size_t)(m0+row)*K + (t+1)*32)*2 + kc*16, ab[cb^1] + (w*2+i)*1024);
      }
      const unsigned short* pn = Wp + ((size_t)(ntg*KS + (t+1)*2)*64 + l)*8;
      nh0 = *(const bf16x8*)(pn);
      nh1 = *(const bf16x8*)(pn + 512);
      nl0 = *(const bf16x8*)(pn + loOff);
      nl1 = *(const bf16x8*)(pn + loOff + 512);
    }
    #pragma unroll
    for (int mt=0;mt<2;mt++){
      int r = mh*64 + mt*32 + (l&31);
      int b0 = (r*64 + (l>>5)*16) ^ (((r>>1)&7)<<4);
      bf16x8 a0 = *(const bf16x8*)(ab[cb] + b0);
      bf16x8 a1 = *(const bf16x8*)(ab[cb] + (b0^32));
      acc[mt] = mfma32(a0, bh0, acc[mt]);
      acc[mt] = mfma32(a1, bh1, acc[mt]);
      acc[mt] = mfma32(a0, bl0, acc[mt]);
      acc[mt] = mfma32(a1, bl1, acc[mt]);
    }
    __syncthreads();
    bh0=nh0; bh1=nh1; bl0=nl0; bl1=nl1;
  }

  const int col = n0 + ntl*32 + (l&31);
  const float bv = bias[col];
  #pragma unroll
  for (int mt=0;mt<2;mt++){
    #pragma unroll
    for (int rg=0;rg<16;rg++){
      int r = m0 + mh*64 + mt*32 + (rg&3) + 8*(rg>>2) + 4*(l>>5);
      float v = acc[mt][rg] + bv;
      if (RELU) v = fmaxf(v, 0.f);
      if (OBF16) ((unsigned short*)out)[(size_t)r*N + col] = f2bf(v);
      else       ((float*)out)[(size_t)r*N + col] = v;
    }
  }
}

// ============ GRU scan: one block per batch element; 4 threads per hidden unit
// v4: in-loop barrier is LDS-only (s_waitcnt lgkmcnt(0); s_barrier) so the per-step
// hid global store and gx/done prefetch loads stay in flight across the barrier
// (no vmcnt(0) drain on the serial critical path). h_prev read hoisted.
__global__ __launch_bounds__(512) void k_gru(const float* __restrict__ gx,
    const float* __restrict__ done, const float* __restrict__ h0,
    const float* __restrict__ whh, const float* __restrict__ bhh,
    float* __restrict__ hid, float* __restrict__ hfin)
{
  __shared__ __align__(16) float hs[2][128];
  const int b = blockIdx.x, tid = threadIdx.x;
  const int u = tid>>2, sub = tid&3;
  f32x2 wr[16], wz[16], wn[16];
  const float* wru = whh + (size_t)u*128 + sub*32;
  const float* wzu = whh + (size_t)(u+128)*128 + sub*32;
  const float* wnu = whh + (size_t)(u+256)*128 + sub*32;
  #pragma unroll
  for (int q=0;q<8;q++){
    const int e = (q + sub*2)&7;                   // runtime SOURCE addr, static DEST index
    float4 a = *(const float4*)(wru + e*4);
    float4 c = *(const float4*)(wzu + e*4);
    float4 d = *(const float4*)(wnu + e*4);
    wr[q*2] = f32x2{a.x,a.y}; wr[q*2+1] = f32x2{a.z,a.w};
    wz[q*2] = f32x2{c.x,c.y}; wz[q*2+1] = f32x2{c.z,c.w};
    wn[q*2] = f32x2{d.x,d.y}; wn[q*2+1] = f32x2{d.z,d.w};
  }
  const float br = bhh[u], bz = bhh[u+128], bn = bhh[u+256];
  if (tid<128) hs[0][tid] = h0[(size_t)b*128+tid];

  // prefetch t=0
  const float* g0 = gx + (size_t)b*384;
  float pg0 = g0[u], pg1 = g0[u+128], pg2 = g0[u+256];
  float pd  = done[b];
  __syncthreads();

  for (int t=0;t<128;t++){
    const int cur = t&1;
    const float gr=pg0, gz=pg1, gn=pg2, dn=pd;
    if (t+1 < 128){
      const float* gp = gx + ((size_t)(t+1)*32+b)*384;
      pg0=gp[u]; pg1=gp[u+128]; pg2=gp[u+256];
      pd = done[(t+1)*32+b];
    }
    const float hpv = hs[cur][u];                  // hoisted: independent of the reduce
    // conflict-free: per q, 4 distinct float4 addrs (one per sub), broadcast to 16 lanes
    const float* hb = &hs[cur][sub*32];
    f32x2 hv[16];
    #pragma unroll
    for (int q=0;q<8;q++){
      const int e = (q + sub*2)&7;                 // runtime LDS addr, static reg index
      float4 v = *(const float4*)(hb + e*4);
      hv[q*2]   = f32x2{v.x,v.y};
      hv[q*2+1] = f32x2{v.z,v.w};
    }
    f32x2 a2r = {0.f,0.f}, a2z = {0.f,0.f}, a2n = {0.f,0.f};
    #pragma unroll
    for (int i=0;i<16;i++){
      a2r += wr[i]*hv[i];
      a2z += wz[i]*hv[i];
      a2n += wn[i]*hv[i];
    }
    float ar=a2r[0]+a2r[1], az=a2z[0]+a2z[1], an=a2n[0]+a2n[1];
    ar += __shfl_xor(ar,1); ar += __shfl_xor(ar,2);
    az += __shfl_xor(az,1); az += __shfl_xor(az,2);
    an += __shfl_xor(an,1); an += __shfl_xor(an,2);
    if (sub==0){
      const float keep = 1.0f - dn;
      const float hp = keep*hpv;
      const float r  = sigmoidf_(gr + keep*ar + br);
      const float z  = sigmoidf_(gz + keep*az + bz);
      const float nn = tanhf_  (gn + r*(keep*an + bn));
      const float hn = (1.0f-z)*nn + z*hp;
      hs[cur^1][u] = hn;                           // LDS write first (lgkm-drained)
      hid[((size_t)t*32+b)*128 + u] = hn;          // global store stays in flight
    }
    // LDS-only barrier: don't drain vmcnt (hid stores / gx prefetch keep flying)
    asm volatile("s_waitcnt lgkmcnt(0)\n\ts_barrier" ::: "memory");
    __builtin_amdgcn_sched_barrier(0);
  }
  if (tid<128) hfin[(size_t)b*128+tid] = hs[0][tid];   // t=127 wrote buffer 0
}

// ============ heads: logits[4096,6], value[4096]
__global__ __launch_bounds__(256) void k_heads(const float* __restrict__ hid,
    const float* __restrict__ aw, const float* __restrict__ ab,
    const float* __restrict__ cw, const float* __restrict__ cb,
    float* __restrict__ out)
{
  __shared__ __align__(16) float wsm[7*128];
  __shared__ float bb[7];
  const int tid = threadIdx.x;
  for (int i=tid;i<896;i+=256) wsm[i] = (i<768) ? aw[i] : cw[i-768];
  if (tid<7) bb[tid] = (tid<6) ? ab[tid] : cb[0];
  __syncthreads();
  const int idx = blockIdx.x*256 + tid;    // < 28672 exactly
  const int n = idx/7, a = idx - n*7;
  const float4* hp = (const float4*)(hid + (size_t)n*128);
  const float4* wp = (const float4*)(&wsm[a*128]);
  float s = bb[a];
  #pragma unroll
  for (int q=0;q<32;q++){
    const float4 h4=hp[q], w4=wp[q];
    s += h4.x*w4.x + h4.y*w4.y + h4.z*w4.z + h4.w*w4.w;
  }
  if (a<6) out[(size_t)n*6+a]=s; else out[24576+n]=s;
}

extern "C" void kernel_launch(void* const* d_in, const int* in_sizes, int n_in,
                              void* d_out, int out_size, void* d_ws, size_t ws_size,
                              hipStream_t stream)
{
  const float* x    = (const float*)d_in[0];
  const float* done = (const float*)d_in[1];
  const float* h0   = (const float*)d_in[2];
  const float* c1w  = (const float*)d_in[3];
  const float* c1b  = (const float*)d_in[4];
  const float* c2w  = (const float*)d_in[5];
  const float* c2b  = (const float*)d_in[6];
  const float* c3w  = (const float*)d_in[7];
  const float* c3b  = (const float*)d_in[8];
  const float* fcw  = (const float*)d_in[9];
  const float* fcb  = (const float*)d_in[10];
  const float* wih  = (const float*)d_in[11];
  const float* whh  = (const float*)d_in[12];
  const float* bih  = (const float*)d_in[13];
  const float* bhh  = (const float*)d_in[14];
  const float* aw   = (const float*)d_in[15];
  const float* ab   = (const float*)d_in[16];
  const float* cw   = (const float*)d_in[17];
  const float* cb   = (const float*)d_in[18];
  float* out = (float*)d_out;
  char* ws = (char*)d_ws;

  // ---- workspace layout (bytes). NOTHING aliases while live. Max used: 102248448 (<147MB known-good).
  unsigned short* W1P  = (unsigned short*)(ws);               // 4096 B
  unsigned short* W2P  = (unsigned short*)(ws + 4096);        // 65536 B
  unsigned short* W3P  = (unsigned short*)(ws + 69632);       // 73728 B
  unsigned short* FCWP = (unsigned short*)(ws + 143360);      // 6422528 B (hi+lo)
  unsigned short* GXWP = (unsigned short*)(ws + 6565888);     // 786432 B (hi+lo)
  // A1 half-batch [7352320, 59781120) : 2048*12800*2
  unsigned short* A1   = (unsigned short*)(ws + 7352320);
  // A2 full [59781120, 102248448) : 4096*5184*2
  unsigned short* A2   = (unsigned short*)(ws + 59781120);
  // A3 full reuses dead A1 zone [7352320, 33042432) : 4096*3136*2
  unsigned short* A3   = (unsigned short*)(ws + 7352320);
  unsigned short* FEAT = (unsigned short*)(ws + 33042432);    // 4194304
  float* GX   = (float*)(ws + 37236736);                      // 6291456
  float* HID  = (float*)(ws + 43528192);                      // 2097152

  static bool attr_set = false;
  if (!attr_set) {
    (void)hipFuncSetAttribute((const void*)k_conv2, hipFuncAttributeMaxDynamicSharedMemorySize, 102400);
    attr_set = true;
  }

  k_prep_w1<<<8, 256, 0, stream>>>(c1w, W1P);
  k_prep_w2<<<128, 256, 0, stream>>>(c2w, W2P);
  k_prep_w3<<<144, 256, 0, stream>>>(c3w, W3P);
  k_prep_fc<<<dim3(196,16), 512, 0, stream>>>(fcw, FCWP);
  k_prep_gx<<<dim3(32,12), 512, 0, stream>>>(wih, GXWP);

  for (int pass=0; pass<2; pass++){
    k_conv1<<<512, 256, 0, stream>>>(x, W1P, c1b, A1, pass*2048);
    k_conv2<<<512, 256, 102400, stream>>>(A1, W2P, c2b, A2, pass*2048);
  }
  k_conv3<<<1024, 256, 0, stream>>>(A2, W3P, c3b, A3);
  k_gemm<true, true ><<<dim3(8,32), 256, 0, stream>>>(A3, 3136, FCWP, 1605632, fcb, (void*)FEAT, 512);
  k_gemm<false,false><<<dim3(6,32), 256, 0, stream>>>(FEAT, 512, GXWP, 196608, bih, (void*)GX, 384);
  k_gru<<<32, 512, 0, stream>>>(GX, done, h0, whh, bhh, HID, out + 28672);
  k_heads<<<112, 256, 0, stream>>>(HID, aw, ab, cw, cb, out);
}

// Round 10
// 342.202 us; speedup vs baseline: 1.0556x; 1.0556x over previous
//
#include <hip/hip_runtime.h>
#include <hip/hip_bf16.h>
#include <stdint.h>

#define DI __device__ __forceinline__

typedef __bf16 bf16x8 __attribute__((ext_vector_type(8)));
typedef __bf16 bf16x4 __attribute__((ext_vector_type(4)));
typedef float f32x16 __attribute__((ext_vector_type(16)));
typedef float f32x2 __attribute__((ext_vector_type(2)));

DI float bf2f(unsigned short u){ return __uint_as_float(((unsigned int)u)<<16); }
DI unsigned short f2bf(float f){
  unsigned int x = __float_as_uint(f);
  x += 0x7fffu + ((x>>16)&1u);           // RNE; inputs are finite
  return (unsigned short)(x>>16);
}
DI float sigmoidf_(float x){ return 1.0f/(1.0f + __expf(-x)); }
DI float tanhf_(float x){ return 2.0f/(1.0f + __expf(-2.0f*x)) - 1.0f; }  // NaN-safe at both extremes

DI void gld_lds16(const void* g, void* l){
  __builtin_amdgcn_global_load_lds((const __attribute__((address_space(1))) void*)g,
                                   (__attribute__((address_space(3))) void*)l, 16, 0, 0);
}
DI f32x16 mfma32(bf16x8 a, bf16x8 b, f32x16 c){
  return __builtin_amdgcn_mfma_f32_32x32x16_bf16(a, b, c, 0, 0, 0);
}

// ============ merged weight prep: all packs in ONE kernel (saves 4 launch gaps) ====
// frag layout: [tile-linear][lane 64][j 8]; per frag: col n=(l&31)+32*nt, k=(l>>5)*8+j
__global__ __launch_bounds__(256) void k_prep_all(
    const float* __restrict__ w1, const float* __restrict__ w2, const float* __restrict__ w3,
    const float* __restrict__ fcw, const float* __restrict__ wih,
    unsigned short* __restrict__ W1P, unsigned short* __restrict__ W2P,
    unsigned short* __restrict__ W3P, unsigned short* __restrict__ FCWP,
    unsigned short* __restrict__ GXWP)
{
  const int blk = blockIdx.x, tid = threadIdx.x;
  if (blk < 8){                                        // conv1: 2048 = 4 kk * 512, /255 folded
    int idx = blk*256 + tid;
    int j=idx&7, l=(idx>>3)&63, kk=idx>>9;
    int oc=l&31, kg=kk*16+((l>>5)<<3)+j;
    W1P[idx] = f2bf(w1[oc*64 + kg] * (1.0f/255.0f));
  } else if (blk < 136){                               // conv2: 32768 = 16 s * 2 kh * 2 nt * 512
    int idx = (blk-8)*256 + tid;
    int j=idx&7, l=(idx>>3)&63, nt=(idx>>9)&1, kh=(idx>>10)&1, s=idx>>11;
    int oc=nt*32+(l&31), ic=kh*16+(l>>5)*8+j, ky=s>>2, kx=s&3;
    W2P[idx] = f2bf(w2[((oc*32+ic)*4+ky)*4+kx]);
  } else if (blk < 280){                               // conv3: 36864 = 9 s * 4 kh * 2 nt * 512
    int idx = (blk-136)*256 + tid;
    int j=idx&7, l=(idx>>3)&63, nt=(idx>>9)&1, kh=(idx>>10)&3, s=idx>>12;
    int oc=nt*32+(l&31), ic=kh*16+(l>>5)*8+j, ky=s/3, kx=s-ky*3;
    W3P[idx] = f2bf(w3[((oc*64+ic)*3+ky)*3+kx]);
  } else if (blk < 6552){                              // FC: 1605632 items; A3 k'=pos*64+c
    int i = (blk-280)*256 + tid;
    int t2 = i&511, rest = i>>9;                       // rest in [0,3136)
    int ks = rest%196, nt = rest/196;
    int j=t2&7, l=t2>>3;
    int n=nt*32+(l&31), k=ks*16+(l>>5)*8+j;
    int c=k&63, pos=k>>6;
    float wv = fcw[(size_t)n*3136 + c*49 + pos];
    unsigned short hi = f2bf(wv);
    FCWP[i] = hi;
    FCWP[1605632 + i] = f2bf(wv - bf2f(hi));           // lo kept (unused by hi-only FC; harmless)
  } else {                                             // GX: 196608 items, hi+lo
    int i = (blk-6552)*256 + tid;
    int t2 = i&511, rest = i>>9;                       // rest in [0,384)
    int ks = rest&31, nt = rest>>5;
    int j=t2&7, l=t2>>3;
    int n=nt*32+(l&31), k=ks*16+(l>>5)*8+j;
    float wv = wih[(size_t)n*512 + k];
    unsigned short hi = f2bf(wv);
    GXWP[i] = hi;
    GXWP[196608 + i] = f2bf(wv - bf2f(hi));
  }
}

// ============ conv1 (MFMA): x[.,1,84,84] -> 8x8 s4 + relu -> A1[nloc][400 pos][32 ic] bf16
__global__ __launch_bounds__(256) void k_conv1(const float* __restrict__ x,
    const unsigned short* __restrict__ w1p, const float* __restrict__ b,
    unsigned short* __restrict__ a1, int nbase)
{
  __shared__ __align__(16) char imgs[4*14784];     // 4 x [84 rows][88 cols] bf16
  const int tid=threadIdx.x, l=tid&63, w=tid>>6;
  const int nloc = blockIdx.x*4 + w;
  char* myimg = imgs + w*14784;
  const float* xp = x + (size_t)(nbase+nloc)*7056;

  for (int it=0; it<28; ++it){
    int idx4 = l + it*64;                          // over 1764 float4s
    if (idx4 < 1764){
      float4 v = *(const float4*)(xp + idx4*4);
      int row = idx4/21, rem = idx4 - row*21;      // 21 float4s per 84-col row
      ushort4 u; u.x=f2bf(v.x); u.y=f2bf(v.y); u.z=f2bf(v.z); u.w=f2bf(v.w);
      *(ushort4*)(myimg + row*176 + rem*8) = u;
    }
  }

  bf16x8 wb[4];
  #pragma unroll
  for (int kk=0;kk<4;kk++) wb[kk] = *(const bf16x8*)(w1p + (kk*64 + l)*8);
  const float bias = b[l&31];
  asm volatile("s_waitcnt lgkmcnt(0)" ::: "memory");   // staging ds_writes drained

  const int kyh = (l>>5);
  unsigned short* obase = a1 + (size_t)nloc*12800;
  for (int mt=0; mt<13; ++mt){
    int p = mt*32 + (l&31);
    p = min(p, 399);                               // clamped lanes broadcast-read row 399
    const int oy = p/20, ox = p - oy*20;
    const int rbyte = oy*4*176 + ox*8;
    f32x16 acc = {};
    #pragma unroll
    for (int kk=0;kk<4;kk++){
      const int a = rbyte + (kk*2 + kyh)*176;
      bf16x8 af;
      *(bf16x4*)&af       = *(const bf16x4*)(myimg + a);
      *((bf16x4*)&af + 1) = *(const bf16x4*)(myimg + a + 8);
      acc = mfma32(af, wb[kk], acc);
    }
    const int oc = l&31;
    #pragma unroll
    for (int rg=0;rg<16;rg++){
      int row = (rg&3) + 8*(rg>>2) + 4*kyh;
      int pos = mt*32 + row;
      if (pos < 400)
        obase[pos*32 + oc] = f2bf(fmaxf(acc[rg] + bias, 0.f));
    }
  }
}

// ============ conv2: A1[nloc][400][32] -> 4x4 s2 + relu -> A2[nbase+nloc][81][64] (MFMA)
__global__ __launch_bounds__(256) void k_conv2(const unsigned short* __restrict__ a1,
    const unsigned short* __restrict__ w2p, const float* __restrict__ b2,
    unsigned short* __restrict__ a2, int nbase)
{
  extern __shared__ __align__(16) char smem[];   // 4*25600
  const int tid=threadIdx.x, l=tid&63, w=tid>>6;
  const int nloc = blockIdx.x*4 + w;
  char* myimg = smem + w*25600;
  const char* gimg = (const char*)(a1 + (size_t)nloc*12800);
  #pragma unroll
  for (int i=0;i<25;i++){
    int o = i*1024 + l*16;
    int q = o ^ (((o>>7)&7)<<4);     // involutive swizzle, pre-applied to source
    gld_lds16(gimg + q, myimg + i*1024);
  }
  __syncthreads();
  int rbase[3];
  #pragma unroll
  for (int mt=0;mt<3;mt++){
    int r = mt*32 + (l&31);
    int oy=r/9, ox=r-oy*9;
    rbase[mt] = 40*oy + 2*ox;        // in_pos at ky=kx=0
  }
  const int grp16 = (l>>5)*16;
  f32x16 acc[3][2] = {};
  #pragma unroll
  for (int ky=0;ky<4;ky++){
    #pragma unroll
    for (int kx=0;kx<4;kx++){
      const int s = ky*4+kx;
      #pragma unroll
      for (int kh=0;kh<2;kh++){
        bf16x8 b0 = *(const bf16x8*)(w2p + (((s*2+kh)*2+0)*64 + l)*8);
        bf16x8 b1 = *(const bf16x8*)(w2p + (((s*2+kh)*2+1)*64 + l)*8);
        #pragma unroll
        for (int mt=0;mt<3;mt++){
          int ip = rbase[mt] + ky*20 + kx;
          ip = min(ip, 399);                       // pad rows read junk; outputs discarded
          int byte = (ip*64 + kh*32 + grp16) ^ (((ip>>1)&7)<<4);
          bf16x8 af = *(const bf16x8*)(myimg + byte);
          acc[mt][0] = mfma32(af, b0, acc[mt][0]);
          acc[mt][1] = mfma32(af, b1, acc[mt][1]);
        }
      }
    }
  }
  const float bias0 = b2[l&31], bias1 = b2[32+(l&31)];
  unsigned short* ob = (unsigned short*)myimg;     // reuse as [96][64] out stage
  #pragma unroll
  for (int mt=0;mt<3;mt++){
    #pragma unroll
    for (int rg=0;rg<16;rg++){
      int r = mt*32 + (rg&3) + 8*(rg>>2) + 4*(l>>5);
      ob[r*64 + (l&31)]      = f2bf(fmaxf(acc[mt][0][rg]+bias0,0.f));
      ob[r*64 + 32 + (l&31)] = f2bf(fmaxf(acc[mt][1][rg]+bias1,0.f));
    }
  }
  asm volatile("s_waitcnt lgkmcnt(0)" ::: "memory");
  const uint4* s4 = (const uint4*)ob;
  uint4* d4 = (uint4*)(a2 + (size_t)(nbase+nloc)*5184);
  #pragma unroll
  for (int i=0;i<11;i++){
    int c = i*64 + l;
    if (c < 648) d4[c] = s4[c];
  }
}

// ============ conv3: A2[n][81][64] -> 3x3 s1 + relu -> A3[n][49][64] bf16 (MFMA)
__global__ __launch_bounds__(256) void k_conv3(const unsigned short* __restrict__ a2,
    const unsigned short* __restrict__ w3p, const float* __restrict__ b3,
    unsigned short* __restrict__ a3)
{
  __shared__ __align__(16) char smem3[4*11264];
  const int tid=threadIdx.x, l=tid&63, w=tid>>6;
  const int n = blockIdx.x*4 + w;
  char* myimg = smem3 + w*11264;
  const char* gimg = (const char*)(a2 + (size_t)n*5184);
  #pragma unroll
  for (int i=0;i<11;i++){
    int c = i*64 + l;
    int cc = min(c, 647);
    int o = cc*16;
    int q = o ^ (((o>>7)&7)<<4);
    gld_lds16(gimg + q, myimg + i*1024);
  }
  __syncthreads();
  int base[2];
  #pragma unroll
  for (int mt=0;mt<2;mt++){
    int r = mt*32 + (l&31);
    int oy=r/7, ox=r-oy*7;
    base[mt] = oy*9 + ox;
  }
  const int grp16 = (l>>5)*16;
  f32x16 acc[2][2] = {};
  #pragma unroll
  for (int ky=0;ky<3;ky++){
    #pragma unroll
    for (int kx=0;kx<3;kx++){
      const int s = ky*3+kx;
      #pragma unroll
      for (int kh=0;kh<4;kh++){
        bf16x8 b0 = *(const bf16x8*)(w3p + (((s*4+kh)*2+0)*64 + l)*8);
        bf16x8 b1 = *(const bf16x8*)(w3p + (((s*4+kh)*2+1)*64 + l)*8);
        #pragma unroll
        for (int mt=0;mt<2;mt++){
          int ip = min(base[mt] + ky*9 + kx, 80);
          int byte = (ip*128 + kh*32 + grp16) ^ ((ip&7)<<4);
          bf16x8 af = *(const bf16x8*)(myimg + byte);
          acc[mt][0] = mfma32(af, b0, acc[mt][0]);
          acc[mt][1] = mfma32(af, b1, acc[mt][1]);
        }
      }
    }
  }
  const float bias0 = b3[l&31], bias1 = b3[32+(l&31)];
  unsigned short* ob = (unsigned short*)myimg;     // [49][64]
  #pragma unroll
  for (int mt=0;mt<2;mt++){
    #pragma unroll
    for (int rg=0;rg<16;rg++){
      int r = mt*32 + (rg&3) + 8*(rg>>2) + 4*(l>>5);
      if (r < 49){
        ob[r*64 + (l&31)]      = f2bf(fmaxf(acc[mt][0][rg]+bias0,0.f));
        ob[r*64 + 32 + (l&31)] = f2bf(fmaxf(acc[mt][1][rg]+bias1,0.f));
      }
    }
  }
  asm volatile("s_waitcnt lgkmcnt(0)" ::: "memory");
  const uint4* s4 = (const uint4*)ob;
  uint4* d4 = (uint4*)(a3 + (size_t)n*3136);
  #pragma unroll
  for (int i=0;i<7;i++){
    int c = i*64 + l;
    if (c < 392) d4[c] = s4[c];
  }
}

// ============ GEMM: out[M,N] = act(A[M,K](bf16) @ W^frag + bias) ; BM=128 BN=64 BK=32
// HILO: add lo-residual MFMAs (w = hi + lo). FC runs hi-only (2x less MFMA + B-traffic).
template<bool RELU, bool OBF16, bool HILO>
__global__ __launch_bounds__(256) void k_gemm(const unsigned short* __restrict__ A, int K,
    const unsigned short* __restrict__ Wp, int loOff, const float* __restrict__ bias,
    void* __restrict__ out, int N)
{
  __shared__ __align__(16) char ab[2][8192];      // [128 rows][32 bf16] x2
  const int tid=threadIdx.x, l=tid&63, w=tid>>6;
  const int m0=blockIdx.y*128, n0=blockIdx.x*64;
  const int KS=K>>4, T=K>>5;
  const int mh=w&1, ntl=w>>1;
  const int ntg = blockIdx.x*2 + ntl;
  const char* Ab = (const char*)A;

  f32x16 acc[2] = {};
  bf16x8 bh0, bh1, bl0, bl1, nh0, nh1, nl0, nl1;

  #pragma unroll
  for (int i=0;i<2;i++){
    int o = (w*2+i)*1024 + l*16;
    int q = o ^ (((o>>7)&7)<<4);
    int row = q>>6, kc=(q>>4)&3;
    gld_lds16(Ab + ((size_t)(m0+row)*K)*2 + kc*16, ab[0] + (w*2+i)*1024);
  }
  {
    const unsigned short* p0 = Wp + ((size_t)(ntg*KS)*64 + l)*8;
    bh0 = *(const bf16x8*)(p0);
    bh1 = *(const bf16x8*)(p0 + 512);
    if (HILO){
      bl0 = *(const bf16x8*)(p0 + loOff);
      bl1 = *(const bf16x8*)(p0 + loOff + 512);
    }
  }
  __syncthreads();

  for (int t=0;t<T;t++){
    const int cb = t&1;
    if (t+1 < T){
      #pragma unroll
      for (int i=0;i<2;i++){
        int o = (w*2+i)*1024 + l*16;
        int q = o ^ (((o>>7)&7)<<4);
        int row = q>>6, kc=(q>>4)&3;
        gld_lds16(Ab + ((size_t)(m0+row)*K + (t+1)*32)*2 + kc*16, ab[cb^1] + (w*2+i)*1024);
      }
      const unsigned short* pn = Wp + ((size_t)(ntg*KS + (t+1)*2)*64 + l)*8;
      nh0 = *(const bf16x8*)(pn);
      nh1 = *(const bf16x8*)(pn + 512);
      if (HILO){
        nl0 = *(const bf16x8*)(pn + loOff);
        nl1 = *(const bf16x8*)(pn + loOff + 512);
      }
    }
    #pragma unroll
    for (int mt=0;mt<2;mt++){
      int r = mh*64 + mt*32 + (l&31);
      int b0 = (r*64 + (l>>5)*16) ^ (((r>>1)&7)<<4);
      bf16x8 a0 = *(const bf16x8*)(ab[cb] + b0);
      bf16x8 a1 = *(const bf16x8*)(ab[cb] + (b0^32));
      acc[mt] = mfma32(a0, bh0, acc[mt]);
      acc[mt] = mfma32(a1, bh1, acc[mt]);
      if (HILO){
        acc[mt] = mfma32(a0, bl0, acc[mt]);
        acc[mt] = mfma32(a1, bl1, acc[mt]);
      }
    }
    __syncthreads();
    bh0=nh0; bh1=nh1;
    if (HILO){ bl0=nl0; bl1=nl1; }
  }

  const int col = n0 + ntl*32 + (l&31);
  const float bv = bias[col];
  #pragma unroll
  for (int mt=0;mt<2;mt++){
    #pragma unroll
    for (int rg=0;rg<16;rg++){
      int r = m0 + mh*64 + mt*32 + (rg&3) + 8*(rg>>2) + 4*(l>>5);
      float v = acc[mt][rg] + bv;
      if (RELU) v = fmaxf(v, 0.f);
      if (OBF16) ((unsigned short*)out)[(size_t)r*N + col] = f2bf(v);
      else       ((float*)out)[(size_t)r*N + col] = v;
    }
  }
}

// ============ GRU scan: one block per batch element; v5: 256 threads, 2 threads/unit
// (64-k slice each) -> single shfl_xor(1) per gate, 4-wave barrier (half the skew),
// fewer LDS-pipe instrs. All register indices static; rotation only in addresses.
__global__ __launch_bounds__(256) void k_gru(const float* __restrict__ gx,
    const float* __restrict__ done, const float* __restrict__ h0,
    const float* __restrict__ whh, const float* __restrict__ bhh,
    float* __restrict__ hid, float* __restrict__ hfin)
{
  __shared__ __align__(16) float hs[2][128];
  const int b = blockIdx.x, tid = threadIdx.x;
  const int u = tid>>1, sub = tid&1;
  f32x2 wr[32], wz[32], wn[32];
  const float* wru = whh + (size_t)u*128 + sub*64;
  const float* wzu = whh + (size_t)(u+128)*128 + sub*64;
  const float* wnu = whh + (size_t)(u+256)*128 + sub*64;
  #pragma unroll
  for (int q=0;q<16;q++){
    const int e = (q + sub*4)&15;                  // runtime SOURCE addr, static DEST index
    float4 a = *(const float4*)(wru + e*4);
    float4 c = *(const float4*)(wzu + e*4);
    float4 d = *(const float4*)(wnu + e*4);
    wr[q*2] = f32x2{a.x,a.y}; wr[q*2+1] = f32x2{a.z,a.w};
    wz[q*2] = f32x2{c.x,c.y}; wz[q*2+1] = f32x2{c.z,c.w};
    wn[q*2] = f32x2{d.x,d.y}; wn[q*2+1] = f32x2{d.z,d.w};
  }
  const float br = bhh[u], bz = bhh[u+128], bn = bhh[u+256];
  if (tid<128) hs[0][tid] = h0[(size_t)b*128+tid];

  // prefetch t=0
  const float* g0 = gx + (size_t)b*384;
  float pg0 = g0[u], pg1 = g0[u+128], pg2 = g0[u+256];
  float pd  = done[b];
  __syncthreads();

  for (int t=0;t<128;t++){
    const int cur = t&1;
    const float gr=pg0, gz=pg1, gn=pg2, dn=pd;
    if (t+1 < 128){
      const float* gp = gx + ((size_t)(t+1)*32+b)*384;
      pg0=gp[u]; pg1=gp[u+128]; pg2=gp[u+256];
      pd = done[(t+1)*32+b];
    }
    const float hpv = hs[cur][u];                  // independent of the reduce
    // conflict-free: per instr, 2 distinct float4 addrs (banks 4q vs 4q+16), 32-lane bcast
    const float* hb = &hs[cur][sub*64];
    f32x2 hv[32];
    #pragma unroll
    for (int q=0;q<16;q++){
      const int e = (q + sub*4)&15;                // runtime LDS addr, static reg index
      float4 v = *(const float4*)(hb + e*4);
      hv[q*2]   = f32x2{v.x,v.y};
      hv[q*2+1] = f32x2{v.z,v.w};
    }
    f32x2 a2r = {0.f,0.f}, a2z = {0.f,0.f}, a2n = {0.f,0.f};
    #pragma unroll
    for (int i=0;i<32;i++){
      a2r += wr[i]*hv[i];
      a2z += wz[i]*hv[i];
      a2n += wn[i]*hv[i];
    }
    float ar=a2r[0]+a2r[1], az=a2z[0]+a2z[1], an=a2n[0]+a2n[1];
    ar += __shfl_xor(ar,1);                        // partner = other sub, same unit
    az += __shfl_xor(az,1);
    an += __shfl_xor(an,1);
    if (sub==0){
      const float keep = 1.0f - dn;
      const float hp = keep*hpv;
      const float r  = sigmoidf_(gr + keep*ar + br);
      const float z  = sigmoidf_(gz + keep*az + bz);
      const float nn = tanhf_  (gn + r*(keep*an + bn));
      const float hn = (1.0f-z)*nn + z*hp;
      hs[cur^1][u] = hn;                           // LDS write (lgkm-drained at barrier)
      hid[((size_t)t*32+b)*128 + u] = hn;          // global store stays in flight
    }
    // LDS-only barrier: don't drain vmcnt
    asm volatile("s_waitcnt lgkmcnt(0)\n\ts_barrier" ::: "memory");
    __builtin_amdgcn_sched_barrier(0);
  }
  if (tid<128) hfin[(size_t)b*128+tid] = hs[0][tid];   // t=127 wrote buffer 0
}

// ============ heads: logits[4096,6], value[4096]
__global__ __launch_bounds__(256) void k_heads(const float* __restrict__ hid,
    const float* __restrict__ aw, const float* __restrict__ ab,
    const float* __restrict__ cw, const float* __restrict__ cb,
    float* __restrict__ out)
{
  __shared__ __align__(16) float wsm[7*128];
  __shared__ float bb[7];
  const int tid = threadIdx.x;
  for (int i=tid;i<896;i+=256) wsm[i] = (i<768) ? aw[i] : cw[i-768];
  if (tid<7) bb[tid] = (tid<6) ? ab[tid] : cb[0];
  __syncthreads();
  const int idx = blockIdx.x*256 + tid;    // < 28672 exactly
  const int n = idx/7, a = idx - n*7;
  const float4* hp = (const float4*)(hid + (size_t)n*128);
  const float4* wp = (const float4*)(&wsm[a*128]);
  float s = bb[a];
  #pragma unroll
  for (int q=0;q<32;q++){
    const float4 h4=hp[q], w4=wp[q];
    s += h4.x*w4.x + h4.y*w4.y + h4.z*w4.z + h4.w*w4.w;
  }
  if (a<6) out[(size_t)n*6+a]=s; else out[24576+n]=s;
}

extern "C" void kernel_launch(void* const* d_in, const int* in_sizes, int n_in,
                              void* d_out, int out_size, void* d_ws, size_t ws_size,
                              hipStream_t stream)
{
  const float* x    = (const float*)d_in[0];
  const float* done = (const float*)d_in[1];
  const float* h0   = (const float*)d_in[2];
  const float* c1w  = (const float*)d_in[3];
  const float* c1b  = (const float*)d_in[4];
  const float* c2w  = (const float*)d_in[5];
  const float* c2b  = (const float*)d_in[6];
  const float* c3w  = (const float*)d_in[7];
  const float* c3b  = (const float*)d_in[8];
  const float* fcw  = (const float*)d_in[9];
  const float* fcb  = (const float*)d_in[10];
  const float* wih  = (const float*)d_in[11];
  const float* whh  = (const float*)d_in[12];
  const float* bih  = (const float*)d_in[13];
  const float* bhh  = (const float*)d_in[14];
  const float* aw   = (const float*)d_in[15];
  const float* ab   = (const float*)d_in[16];
  const float* cw   = (const float*)d_in[17];
  const float* cb   = (const float*)d_in[18];
  float* out = (float*)d_out;
  char* ws = (char*)d_ws;

  // ---- workspace layout (bytes). NOTHING aliases while live. Max used: 102248448 (<147MB known-good).
  unsigned short* W1P  = (unsigned short*)(ws);               // 4096 B
  unsigned short* W2P  = (unsigned short*)(ws + 4096);        // 65536 B
  unsigned short* W3P  = (unsigned short*)(ws + 69632);       // 73728 B
  unsigned short* FCWP = (unsigned short*)(ws + 143360);      // 6422528 B (hi+lo)
  unsigned short* GXWP = (unsigned short*)(ws + 6565888);     // 786432 B (hi+lo)
  // A1 half-batch [7352320, 59781120) : 2048*12800*2
  unsigned short* A1   = (unsigned short*)(ws + 7352320);
  // A2 full [59781120, 102248448) : 4096*5184*2
  unsigned short* A2   = (unsigned short*)(ws + 59781120);
  // A3 full reuses dead A1 zone [7352320, 33042432) : 4096*3136*2
  unsigned short* A3   = (unsigned short*)(ws + 7352320);
  unsigned short* FEAT = (unsigned short*)(ws + 33042432);    // 4194304
  float* GX   = (float*)(ws + 37236736);                      // 6291456
  float* HID  = (float*)(ws + 43528192);                      // 2097152

  static bool attr_set = false;
  if (!attr_set) {
    (void)hipFuncSetAttribute((const void*)k_conv2, hipFuncAttributeMaxDynamicSharedMemorySize, 102400);
    attr_set = true;
  }

  k_prep_all<<<7320, 256, 0, stream>>>(c1w, c2w, c3w, fcw, wih, W1P, W2P, W3P, FCWP, GXWP);

  for (int pass=0; pass<2; pass++){
    k_conv1<<<512, 256, 0, stream>>>(x, W1P, c1b, A1, pass*2048);
    k_conv2<<<512, 256, 102400, stream>>>(A1, W2P, c2b, A2, pass*2048);
  }
  k_conv3<<<1024, 256, 0, stream>>>(A2, W3P, c3b, A3);
  k_gemm<true, true, false><<<dim3(8,32), 256, 0, stream>>>(A3, 3136, FCWP, 0, fcb, (void*)FEAT, 512);
  k_gemm<false,false,true ><<<dim3(6,32), 256, 0, stream>>>(FEAT, 512, GXWP, 196608, bih, (void*)GX, 384);
  k_gru<<<32, 256, 0, stream>>>(GX, done, h0, whh, bhh, HID, out + 28672);
  k_heads<<<112, 256, 0, stream>>>(HID, aw, ab, cw, cb, out);
}